// Round 2
// baseline (289.799 us; speedup 1.0000x reference)
//
#include <hip/hip_runtime.h>
#include <math.h>

#define VOCAB 32000
#define NROWS 4096
#define PAD_IDX 0

// ext_vector so __builtin_nontemporal_load accepts it (HIP float4 is a class)
typedef float f4 __attribute__((ext_vector_type(4)));

// One block per row: stream the row with non-temporal float4 loads, closed-form
// per-row KL contribution, then "last block" (threadfence + atomic counter)
// deterministically reduces the 4096 partials and writes the scalar output.
//
// Closed form per non-pad row r with gold t:
//   eps = 0.1/(V-2);  C = 0.1*ln(eps) + 0.9*ln(0.9)   (eps*(V-2) == 0.1 exactly)
//   contrib = C - eps*(rowsum - x[r,0] - x[r,t]) - 0.9*x[r,t]
__global__ __launch_bounds__(256) void ls_fused(const float* __restrict__ x,
                                                const int* __restrict__ target,
                                                float* __restrict__ partials,
                                                unsigned* __restrict__ counter,
                                                float* __restrict__ out) {
    const int row = blockIdx.x;
    const float* xr = x + (size_t)row * VOCAB;
    const int tid = threadIdx.x;

    const f4* x4 = reinterpret_cast<const f4*>(xr);   // rows are 16B-aligned (32000*4 % 16 == 0)
    float s = 0.f;
    #pragma unroll 4
    for (int i = tid; i < VOCAB / 4; i += 256) {
        f4 v = __builtin_nontemporal_load(&x4[i]);    // streamed once, no reuse
        s += (v.x + v.y) + (v.z + v.w);
    }

    // wave-64 butterfly-free down-reduce
    for (int off = 32; off > 0; off >>= 1)
        s += __shfl_down(s, off, 64);

    __shared__ float ws_s[4];
    __shared__ bool  is_last;
    const int wave = tid >> 6;
    const int lane = tid & 63;
    if (lane == 0) ws_s[wave] = s;
    __syncthreads();

    if (tid == 0) {
        float rowsum = (ws_s[0] + ws_s[1]) + (ws_s[2] + ws_s[3]);
        const int t = target[row];
        float contrib = 0.f;
        if (t != PAD_IDX) {
            const float eps = 0.1f / (float)(VOCAB - 2);
            const float C   = 0.1f * logf(eps) + 0.9f * logf(0.9f);
            const float x0  = xr[0];
            const float xt  = xr[t];
            contrib = C - eps * (rowsum - x0 - xt) - 0.9f * xt;
        }
        partials[row] = contrib;
        __threadfence();                        // device-scope release of partials[row]
        unsigned old = atomicAdd(counter, 1u);  // device-scope atomic
        is_last = (old == NROWS - 1);
    }
    __syncthreads();

    if (is_last) {
        __threadfence();   // acquire: invalidate stale L1/L2 before reading partials
        float t = 0.f;
        for (int i = tid; i < NROWS; i += 256)  // 16 values/thread, fixed order
            t += partials[i];
        for (int off = 32; off > 0; off >>= 1)
            t += __shfl_down(t, off, 64);
        if (lane == 0) ws_s[wave] = t;
        __syncthreads();
        if (tid == 0)
            *out = (ws_s[0] + ws_s[1]) + (ws_s[2] + ws_s[3]);   // overwrite poisoned d_out
    }
}

extern "C" void kernel_launch(void* const* d_in, const int* in_sizes, int n_in,
                              void* d_out, int out_size, void* d_ws, size_t ws_size,
                              hipStream_t stream) {
    const float* x      = (const float*)d_in[0];
    const int*   target = (const int*)d_in[1];
    float*    out      = (float*)d_out;
    float*    partials = (float*)d_ws;                    // 4096 floats
    unsigned* counter  = (unsigned*)((char*)d_ws + NROWS * sizeof(float));

    // d_ws is poisoned once (0xAA) and never re-poisoned: zero the counter each
    // call so every graph replay starts consistent (stream-ordered, capturable).
    hipMemsetAsync(counter, 0, sizeof(unsigned), stream);

    ls_fused<<<NROWS, 256, 0, stream>>>(x, target, partials, counter, out);
}

// Round 3
// 130.797 us; speedup vs baseline: 2.2157x; 2.2157x over previous
//
#include <hip/hip_runtime.h>
#include <math.h>

#define VOCAB 32000
#define NROWS 4096
#define PAD_IDX 0

// One block per row: stream the row with cached float4 loads, closed-form
// per-row KL contribution, then "last block" pattern reduces the 4096 partials.
//
// Coherence design (avoid buffer_wbl2 — a full-L2 writeback walk — entirely):
//  - partials[row] written with RELAXED agent-scope atomic store (sc-flagged,
//    write-through to the agent coherence point; no dirty L2 state)
//  - explicit s_waitcnt vmcnt(0) ensures the store is ack'd at the coherence
//    point before the counter RMW issues
//  - counter RMW is RELAXED agent-scope; RMWs serialize at the coherence point,
//    so the block that observes NROWS-1 knows all partial stores are visible
//  - last block reads partials with RELAXED agent-scope atomic loads (bypass
//    potentially-stale local caches)
//
// Closed form per non-pad row r with gold t (eps*(V-2) == 0.1 exactly):
//   eps = 0.1/(V-2);  C = 0.1*ln(eps) + 0.9*ln(0.9)
//   contrib = C - eps*(rowsum - x[r,0] - x[r,t]) - 0.9*x[r,t]
__global__ __launch_bounds__(256) void ls_fused(const float* __restrict__ x,
                                                const int* __restrict__ target,
                                                float* __restrict__ partials,
                                                unsigned* __restrict__ counter,
                                                float* __restrict__ out) {
    const int row = blockIdx.x;
    const float* xr = x + (size_t)row * VOCAB;
    const int tid = threadIdx.x;

    const float4* x4 = reinterpret_cast<const float4*>(xr);  // 32000*4 % 16 == 0
    float s = 0.f;
    for (int i = tid; i < VOCAB / 4; i += 256) {
        float4 v = x4[i];
        s += (v.x + v.y) + (v.z + v.w);
    }

    // wave-64 reduce
    for (int off = 32; off > 0; off >>= 1)
        s += __shfl_down(s, off, 64);

    __shared__ float ws_s[4];
    __shared__ bool  is_last;
    const int wave = tid >> 6;
    const int lane = tid & 63;
    if (lane == 0) ws_s[wave] = s;
    __syncthreads();

    if (tid == 0) {
        float rowsum = (ws_s[0] + ws_s[1]) + (ws_s[2] + ws_s[3]);
        const int t = target[row];
        float contrib = 0.f;
        if (t != PAD_IDX) {
            const float eps = 0.1f / (float)(VOCAB - 2);
            const float C   = 0.1f * logf(eps) + 0.9f * logf(0.9f);
            const float x0  = xr[0];
            const float xt  = xr[t];
            contrib = C - eps * (rowsum - x0 - xt) - 0.9f * xt;
        }
        __hip_atomic_store(&partials[row], contrib,
                           __ATOMIC_RELAXED, __HIP_MEMORY_SCOPE_AGENT);
        asm volatile("s_waitcnt vmcnt(0)" ::: "memory");  // store ack'd at coherence point
        unsigned old = __hip_atomic_fetch_add(counter, 1u,
                           __ATOMIC_RELAXED, __HIP_MEMORY_SCOPE_AGENT);
        is_last = (old == NROWS - 1);
    }
    __syncthreads();

    if (is_last) {
        float t = 0.f;
        for (int i = tid; i < NROWS; i += 256)   // 16 values/thread, fixed order
            t += __hip_atomic_load(&partials[i],
                     __ATOMIC_RELAXED, __HIP_MEMORY_SCOPE_AGENT);
        for (int off = 32; off > 0; off >>= 1)
            t += __shfl_down(t, off, 64);
        if (lane == 0) ws_s[wave] = t;
        __syncthreads();
        if (tid == 0)
            *out = (ws_s[0] + ws_s[1]) + (ws_s[2] + ws_s[3]);  // overwrite poisoned d_out
    }
}

extern "C" void kernel_launch(void* const* d_in, const int* in_sizes, int n_in,
                              void* d_out, int out_size, void* d_ws, size_t ws_size,
                              hipStream_t stream) {
    const float* x      = (const float*)d_in[0];
    const int*   target = (const int*)d_in[1];
    float*    out      = (float*)d_out;
    float*    partials = (float*)d_ws;                    // 4096 floats
    unsigned* counter  = (unsigned*)((char*)d_ws + NROWS * sizeof(float));

    // d_ws poisoned once (0xAA), never re-poisoned: zero the counter every call
    // (stream-ordered, graph-capturable).
    hipMemsetAsync(counter, 0, sizeof(unsigned), stream);

    ls_fused<<<NROWS, 256, 0, stream>>>(x, target, partials, counter, out);
}

// Round 5
// 97.103 us; speedup vs baseline: 2.9845x; 1.3470x over previous
//
#include <hip/hip_runtime.h>
#include <math.h>

#define VOCAB 32000
#define NROWS 4096
#define PAD_IDX 0

// One block per row: stream the row (float4, coalesced), closed-form per-row
// KL contribution, partial to d_ws. Kernel boundary provides cross-XCD
// coherence (fused variants measured slower: 290us threadfence, 131us
// relaxed-atomic, vs 96us two-kernel).
//
// Closed form per non-pad row r with gold t (eps*(V-2) == 0.1 exactly):
//   eps = 0.1/(V-2);  C = 0.1*ln(eps) + 0.9*ln(0.9)
//   contrib = C - eps*(rowsum - x[r,0] - x[r,t]) - 0.9*x[r,t]
__global__ __launch_bounds__(256) void ls_row_kernel(const float* __restrict__ x,
                                                     const int* __restrict__ target,
                                                     float* __restrict__ partials) {
    const int row = blockIdx.x;
    const float* xr = x + (size_t)row * VOCAB;
    const int tid = threadIdx.x;

    // Prefetch the epilogue gather on tid 0 BEFORE the streaming loop so its
    // HBM latency overlaps the row stream.
    int   t  = 0;
    float x0 = 0.f, xt = 0.f;
    if (tid == 0) {
        t  = target[row];
        x0 = xr[0];
        xt = xr[(t != PAD_IDX) ? t : 0];
    }

    // 8000 float4 per row. Paired loads, two accumulators (ILP). Coverage
    // (verified by enumeration): element index j = tid + 256*m, m in [0,32);
    // pair iter q covers m=2q (i) and m=2q+1 (i+256) while i+256 < 8000;
    //  - tid<64:  q=0..15 covers m=0..31 (max j = 63+7936 = 7999), tail skipped
    //  - tid>=64: q=0..14 covers m=0..29, tail covers m=30 (i = tid+7680 < 8000)
    const float4* x4 = reinterpret_cast<const float4*>(xr);  // 32000*4 % 16 == 0
    float s0 = 0.f, s1 = 0.f;
    int i = tid;
    for (; i + 256 < VOCAB / 4; i += 512) {
        float4 a = x4[i];
        float4 b = x4[i + 256];
        s0 += (a.x + a.y) + (a.z + a.w);
        s1 += (b.x + b.y) + (b.z + b.w);
    }
    if (i < VOCAB / 4) {
        float4 a = x4[i];
        s0 += (a.x + a.y) + (a.z + a.w);
    }
    float s = s0 + s1;

    // wave-64 reduce
    for (int off = 32; off > 0; off >>= 1)
        s += __shfl_down(s, off, 64);

    __shared__ float ws_s[4];
    const int wave = tid >> 6;
    const int lane = tid & 63;
    if (lane == 0) ws_s[wave] = s;
    __syncthreads();

    if (tid == 0) {
        float rowsum = (ws_s[0] + ws_s[1]) + (ws_s[2] + ws_s[3]);
        float contrib = 0.f;
        if (t != PAD_IDX) {
            const float eps = 0.1f / (float)(VOCAB - 2);
            const float C   = 0.1f * logf(eps) + 0.9f * logf(0.9f);
            contrib = C - eps * (rowsum - x0 - xt) - 0.9f * xt;
        }
        partials[row] = contrib;
    }
}

// Single-block deterministic reduction of the 4096 row partials.
__global__ __launch_bounds__(1024) void ls_reduce_kernel(const float* __restrict__ partials,
                                                         float* __restrict__ out) {
    const int tid = threadIdx.x;
    float s = 0.f;
    for (int i = tid; i < NROWS; i += 1024)
        s += partials[i];

    for (int off = 32; off > 0; off >>= 1)
        s += __shfl_down(s, off, 64);

    __shared__ float ws[16];
    const int wave = tid >> 6;
    const int lane = tid & 63;
    if (lane == 0) ws[wave] = s;
    __syncthreads();

    if (tid == 0) {
        float tot = 0.f;
        for (int w = 0; w < 16; ++w) tot += ws[w];
        *out = tot;   // overwrite (d_out poisoned, never re-zeroed)
    }
}

extern "C" void kernel_launch(void* const* d_in, const int* in_sizes, int n_in,
                              void* d_out, int out_size, void* d_ws, size_t ws_size,
                              hipStream_t stream) {
    const float* x      = (const float*)d_in[0];
    const int*   target = (const int*)d_in[1];
    float* out      = (float*)d_out;
    float* partials = (float*)d_ws;   // 4096 floats

    ls_row_kernel<<<NROWS, 256, 0, stream>>>(x, target, partials);
    ls_reduce_kernel<<<1, 1024, 0, stream>>>(partials, out);
}

// Round 6
// 83.197 us; speedup vs baseline: 3.4833x; 1.1671x over previous
//
#include <hip/hip_runtime.h>
#include <math.h>

#define VOCAB 32000
#define NROWS 4096
#define PAD_IDX 0

// ext_vector so __builtin_nontemporal_load accepts it (HIP float4 is a class)
typedef float f4v __attribute__((ext_vector_type(4)));

// One block per row: stream the row (float4 nt loads, coalesced), closed-form
// per-row KL contribution, partial to d_ws. Kernel boundary provides cross-XCD
// coherence (fused variants measured slower: 290us threadfence, 131us
// relaxed-atomic, vs 96us two-kernel). ILP pairing measured neutral (R5);
// simple stride loop kept.
//
// Closed form per non-pad row r with gold t (eps*(V-2) == 0.1 exactly):
//   eps = 0.1/(V-2);  C = 0.1*ln(eps) + 0.9*ln(0.9)
//   contrib = C - eps*(rowsum - x[r,0] - x[r,t]) - 0.9*x[r,t]
__global__ __launch_bounds__(256) void ls_row_kernel(const float* __restrict__ x,
                                                     const int* __restrict__ target,
                                                     float* __restrict__ partials) {
    const int row = blockIdx.x;
    const float* xr = x + (size_t)row * VOCAB;
    const int tid = threadIdx.x;

    // Prefetch the epilogue gather on tid 0 BEFORE the streaming loop so its
    // HBM latency overlaps the row stream.
    int   t  = 0;
    float x0 = 0.f, xt = 0.f;
    if (tid == 0) {
        t  = target[row];
        x0 = xr[0];
        xt = xr[(t != PAD_IDX) ? t : 0];
    }

    // 32000 floats = 8000 float4 per row, stride-256 across the block.
    // Non-temporal: single-use stream, evict-first in TCC.
    const f4v* x4 = reinterpret_cast<const f4v*>(xr);  // 32000*4 % 16 == 0
    float s = 0.f;
    for (int i = tid; i < VOCAB / 4; i += 256) {
        f4v v = __builtin_nontemporal_load(&x4[i]);
        s += (v[0] + v[1]) + (v[2] + v[3]);
    }

    // wave-64 reduce
    for (int off = 32; off > 0; off >>= 1)
        s += __shfl_down(s, off, 64);

    __shared__ float ws_s[4];
    const int wave = tid >> 6;
    const int lane = tid & 63;
    if (lane == 0) ws_s[wave] = s;
    __syncthreads();

    if (tid == 0) {
        float rowsum = (ws_s[0] + ws_s[1]) + (ws_s[2] + ws_s[3]);
        float contrib = 0.f;
        if (t != PAD_IDX) {
            const float eps = 0.1f / (float)(VOCAB - 2);
            const float C   = 0.1f * logf(eps) + 0.9f * logf(0.9f);
            contrib = C - eps * (rowsum - x0 - xt) - 0.9f * xt;
        }
        partials[row] = contrib;
    }
}

// Single-block deterministic reduction of the 4096 row partials.
__global__ __launch_bounds__(1024) void ls_reduce_kernel(const float* __restrict__ partials,
                                                         float* __restrict__ out) {
    const int tid = threadIdx.x;
    float s = 0.f;
    for (int i = tid; i < NROWS; i += 1024)
        s += partials[i];

    for (int off = 32; off > 0; off >>= 1)
        s += __shfl_down(s, off, 64);

    __shared__ float ws[16];
    const int wave = tid >> 6;
    const int lane = tid & 63;
    if (lane == 0) ws[wave] = s;
    __syncthreads();

    if (tid == 0) {
        float tot = 0.f;
        for (int w = 0; w < 16; ++w) tot += ws[w];
        *out = tot;   // overwrite (d_out poisoned, never re-zeroed)
    }
}

extern "C" void kernel_launch(void* const* d_in, const int* in_sizes, int n_in,
                              void* d_out, int out_size, void* d_ws, size_t ws_size,
                              hipStream_t stream) {
    const float* x      = (const float*)d_in[0];
    const int*   target = (const int*)d_in[1];
    float* out      = (float*)d_out;
    float* partials = (float*)d_ws;   // 4096 floats

    ls_row_kernel<<<NROWS, 256, 0, stream>>>(x, target, partials);
    ls_reduce_kernel<<<1, 1024, 0, stream>>>(partials, out);
}